// Round 3
// baseline (642.869 us; speedup 1.0000x reference)
//
#include <hip/hip_runtime.h>
#include <hip/hip_bf16.h>

#define N_NODES 1000000
#define D_FEAT 128
#define BATCH 100000
#define NUM_SAMPLE 10

typedef float f4 __attribute__((ext_vector_type(4)));

// 32 threads per ROW-PAIR slice: each thread owns one float4 column of TWO
// consecutive output rows. All 20 indices preloaded first, then 20 fully
// independent 16B gathers in flight at once (vs 10 before).
__global__ __launch_bounds__(256) void mean_agg_kernel(
    const f4* __restrict__ feat,   // [N_NODES * 32] f4
    const int* __restrict__ idx,   // [BATCH * NUM_SAMPLE]
    f4* __restrict__ out)          // [BATCH * 32] f4
{
    const int gid  = blockIdx.x * blockDim.x + threadIdx.x;
    const int col  = gid & 31;           // f4 column within row
    const int pair = gid >> 5;           // which row-pair
    if (pair >= BATCH / 2) return;
    const int r0 = pair * 2;

    // Preload all 20 indices (contiguous 80 B, cache-broadcast across lanes).
    const int* __restrict__ ip = idx + r0 * NUM_SAMPLE;
    int id0[NUM_SAMPLE], id1[NUM_SAMPLE];
#pragma unroll
    for (int s = 0; s < NUM_SAMPLE; ++s) {
        id0[s] = ip[s];
        id1[s] = ip[NUM_SAMPLE + s];
    }

    f4 a0 = (f4)(0.f);
    f4 a1 = (f4)(0.f);
#pragma unroll
    for (int s = 0; s < NUM_SAMPLE; ++s) {
        const f4 v0 = feat[(long long)id0[s] * 32 + col];
        const f4 v1 = feat[(long long)id1[s] * 32 + col];
        a0 += v0;
        a1 += v1;
    }

    const float inv = 1.0f / (float)NUM_SAMPLE;
    a0 *= inv;
    a1 *= inv;

    __builtin_nontemporal_store(a0, &out[(long long)r0 * 32 + col]);
    __builtin_nontemporal_store(a1, &out[(long long)(r0 + 1) * 32 + col]);
}

extern "C" void kernel_launch(void* const* d_in, const int* in_sizes, int n_in,
                              void* d_out, int out_size, void* d_ws, size_t ws_size,
                              hipStream_t stream) {
    const f4* feat = (const f4*)d_in[0];
    const int* idx = (const int*)d_in[1];
    f4* out = (f4*)d_out;

    const int total_threads = (BATCH / 2) * 32;       // 1.6M
    const int block = 256;
    const int grid = (total_threads + block - 1) / block;  // 6250
    mean_agg_kernel<<<grid, block, 0, stream>>>(feat, idx, out);
}